// Round 10
// baseline (215.933 us; speedup 1.0000x reference)
//
#include <hip/hip_runtime.h>
#include <stdint.h>

typedef unsigned short u16;
typedef __attribute__((ext_vector_type(8))) short s16x8;   // 8 x bf16 (4 VGPRs)
typedef __attribute__((ext_vector_type(4))) float f32x4;   // MFMA accumulator

__device__ __forceinline__ f32x4 mfma16x16(s16x8 a, s16x8 b, f32x4 c) {
    return __builtin_amdgcn_mfma_f32_16x16x32_bf16(a, b, c, 0, 0, 0);
}

__device__ __forceinline__ u16 f2bf(float f) {
    union { float f; unsigned u; } c; c.f = f;
    unsigned u = c.u;
    return (u16)((u + 0x7FFFu + ((u >> 16) & 1u)) >> 16);   // RNE
}

// global -> LDS direct 16B load. LDS dest = wave-uniform base + lane*16.
__device__ __forceinline__ void gload16(const void* g, void* l) {
    auto gp = (const __attribute__((address_space(1))) unsigned int*)(g);
    auto lp = (__attribute__((address_space(3))) unsigned int*)(l);
    __builtin_amdgcn_global_load_lds(gp, lp, 16, 0, 0);
}

__device__ __forceinline__ void wave_sync() {
    __builtin_amdgcn_sched_barrier(0);
    asm volatile("s_waitcnt vmcnt(0) lgkmcnt(0)" ::: "memory");
    __builtin_amdgcn_sched_barrier(0);
    __builtin_amdgcn_s_barrier();
    __builtin_amdgcn_sched_barrier(0);
}

// ---------------------------------------------------------------------------
__global__ __launch_bounds__(256) void convert_x(
    const float* __restrict__ src, u16* __restrict__ dst, long n)
{
    const long stride = (long)gridDim.x * 256 * 8;
    for (long i = ((long)blockIdx.x * 256 + threadIdx.x) * 8; i < n; i += stride) {
        const float4 a = *(const float4*)(src + i);
        const float4 b = *(const float4*)(src + i + 4);
        u16 o[8] = { f2bf(a.x), f2bf(a.y), f2bf(a.z), f2bf(a.w),
                     f2bf(b.x), f2bf(b.y), f2bf(b.z), f2bf(b.w) };
        *(s16x8*)(dst + i) = *(const s16x8*)o;
    }
}

__global__ __launch_bounds__(256) void fill_sentinel(float* __restrict__ o, long n)
{
    const long stride = (long)gridDim.x * 256;
    for (long i = (long)blockIdx.x * 256 + threadIdx.x; i < n; i += stride)
        o[i] = 1.0f;
}

__global__ __launch_bounds__(256) void transpose_f32_bf16(
    const float* __restrict__ in, u16* __restrict__ out, int R, int C)
{
    __shared__ u16 t[32][33];
    const int c0 = blockIdx.x * 32, r0 = blockIdx.y * 32;
    const int tx = threadIdx.x & 31, ty = threadIdx.x >> 5;
#pragma unroll
    for (int i = 0; i < 32; i += 8)
        t[ty + i][tx] = f2bf(in[(long)(r0 + ty + i) * C + c0 + tx]);
    __syncthreads();
#pragma unroll
    for (int i = 0; i < 32; i += 8)
        out[(long)(c0 + ty + i) * R + r0 + tx] = t[tx][ty + i];
}

// ---------------------------------------------------------------------------
// 128x256 GEMM, 4 waves, 2 blocks/CU (32 KB static LDS: A-only dbuf).
// R10 structural changes vs R9 (targets joint-stall coverage):
//  * B NEVER touches LDS: each wave loads its B fragments straight to
//    registers (16 rows x 64B sectors, L2/L3-hot weights), double-buffered
//    one tile ahead; compiler's register-dep vmcnt waits handle them and
//    provably drain the A-DMA (DMA issued before B loads each tile).
//  * 2 blocks/CU: when one block gates/barriers, the other feeds MFMA.
//  * 1 barrier per K-tile (boundary only); LDS traffic/CU down 33%.
// A LDS layout: [buf][row 0..127][128B row], chunk c of row r stored at
// chunk c^(r&7); frag read byte = row*128 + ((kk*64+g*16) ^ ((r&7)<<4))
// -> uniform 8-access/bank (b128 optimum), zero conflicts.
// ---------------------------------------------------------------------------
template <int FP32OUT, int NT, int NBN>
__global__ __launch_bounds__(256, 2) void gemm128x256(
    const u16* __restrict__ A, const u16* __restrict__ BT,
    const float* __restrict__ bias, void* __restrict__ Cout,
    int N, int K)
{
    __shared__ u16 As[2][8192];      // 2 x 16 KB

    const int tid  = threadIdx.x;
    const int lane = tid & 63;
    const int wid  = tid >> 6;       // wave = n-column 0..3
    const int rr   = lane & 15, g = lane >> 4;

    const int nwg = gridDim.x;
    const int gsw = ((int)blockIdx.x & 7) * (nwg >> 3) + ((int)blockIdx.x >> 3);
    const long m0 = (long)(gsw / NBN) * 128;   // n-fastest within XCD
    const long n0 = (long)(gsw % NBN) * 256;

    // A staging: pass p covers rows (wid*4+p)*8 .. +7, lane l -> row +l/8,
    // source chunk (l&7)^(row&7); dest = wave-uniform (wid*4+p)*1024 + l*16.
    const u16* pA[4];
    int ldst[4];
#pragma unroll
    for (int p = 0; p < 4; ++p) {
        const int r = (wid * 4 + p) * 8 + (lane >> 3);
        const int c = (lane & 7) ^ (r & 7);
        pA[p]   = A + (m0 + r) * (long)K + c * 8;
        ldst[p] = (wid * 4 + p) * 1024;
    }
    // B fragment pointers (per n-subtile)
    const u16* pB[4];
#pragma unroll
    for (int n = 0; n < 4; ++n)
        pB[n] = BT + (n0 + wid * 64 + n * 16 + rr) * (long)K + g * 8;

    // A frag read byte offsets per kk (add m*2048 + buf)
    int aoff[2];
#pragma unroll
    for (int kk = 0; kk < 2; ++kk)
        aoff[kk] = rr * 128 + ((kk * 64 + g * 16) ^ ((rr & 7) << 4));

#define STA(tt) { char* d_ = (char*)As[(tt) & 1];                             \
    _Pragma("unroll") for (int p_ = 0; p_ < 4; ++p_)                          \
        gload16(pA[p_] + (long)(tt) * 64, d_ + ldst[p_]); }
#define LDB(dst, tt, kk) { _Pragma("unroll") for (int n_ = 0; n_ < 4; ++n_)   \
    dst[n_] = *(const s16x8*)(pB[n_] + (long)(tt) * 64 + (kk) * 32); }
#define SB() __builtin_amdgcn_sched_barrier(0)

    f32x4 acc[8][4] = {};
    s16x8 B0a[4], B1a[4], B0b[4], B1b[4];

    // prologue: stage A(0), load B(0).kk0; vmcnt(4) drains the 4 A-DMA.
    STA(0);
    LDB(B0a, 0, 0);
    asm volatile("s_waitcnt vmcnt(4)" ::: "memory");
    SB(); __builtin_amdgcn_s_barrier(); SB();

#define SUBCLUSTER(bufi, kk, mb, Bf)                                          \
    { s16x8 fA[4];                                                            \
      _Pragma("unroll") for (int m_ = 0; m_ < 4; ++m_)                        \
          fA[m_] = *(const s16x8*)((const char*)As[bufi] +                    \
                    ((mb) + m_) * 2048 + aoff[kk]);                           \
      SB();                                                                   \
      __builtin_amdgcn_s_setprio(1);                                          \
      _Pragma("unroll") for (int m_ = 0; m_ < 4; ++m_)                        \
      _Pragma("unroll") for (int n_ = 0; n_ < 4; ++n_)                        \
          acc[(mb) + m_][n_] = mfma16x16(fA[m_], Bf[n_], acc[(mb) + m_][n_]); \
      __builtin_amdgcn_s_setprio(0);                                          \
      SB(); }

#define TILE(t_, Bc0, Bc1, Bn0)                                               \
    {                                                                         \
        if ((t_) + 1 < NT) STA((t_) + 1);                                     \
        LDB(Bc1, (t_), 1);                                                    \
        SUBCLUSTER((t_) & 1, 0, 0, Bc0)                                       \
        SUBCLUSTER((t_) & 1, 0, 4, Bc0)                                       \
        if ((t_) + 1 < NT) LDB(Bn0, (t_) + 1, 0);                             \
        SUBCLUSTER((t_) & 1, 1, 0, Bc1)                                       \
        SUBCLUSTER((t_) & 1, 1, 4, Bc1)                                       \
        if ((t_) < NT - 1) {                                                  \
            asm volatile("s_waitcnt vmcnt(4)" ::: "memory");                  \
            SB(); __builtin_amdgcn_s_barrier(); SB();                         \
        }                                                                     \
    }

    for (int i = 0; i < NT / 2; ++i) {
        TILE(2 * i,     B0a, B1a, B0b)
        TILE(2 * i + 1, B0b, B1b, B0a)
    }
#undef TILE
#undef SUBCLUSTER
#undef STA
#undef LDB
#undef SB

    // epilogue: n innermost (L2 write-merge)
    float bv[4];
#pragma unroll
    for (int n = 0; n < 4; ++n)
        bv[n] = bias[n0 + wid * 64 + n * 16 + rr];
#pragma unroll
    for (int m = 0; m < 8; ++m) {
        const long rb = m0 + m * 16 + g * 4;
#pragma unroll
        for (int r = 0; r < 4; ++r) {
            const long rowoff = (rb + r) * N + n0 + wid * 64 + rr;
#pragma unroll
            for (int n = 0; n < 4; ++n) {
                const float v = acc[m][n][r] + bv[n];
                if (FP32OUT) ((float*)Cout)[rowoff + n * 16] = v;
                else         ((u16*)Cout)[rowoff + n * 16] = f2bf(v);
            }
        }
    }
}

// ---------------------------------------------------------------------------
// Factored attention: one wave per (b, h, p). Attention over NB=64 blocks.
// ---------------------------------------------------------------------------
__global__ __launch_bounds__(64) void attn_blocks(
    const u16* __restrict__ qkv, u16* __restrict__ o)
{
    __shared__ u16 Vlds[64 * 64];
    __shared__ u16 Plds[64 * 72];
    const int bid = blockIdx.x;
    const int b = bid >> 11;
    const int h = (bid >> 7) & 15;
    const int p = bid & 127;
    const int lane = threadIdx.x;
    const int rr = lane & 15, g = lane >> 4;
    const long NSTR = 128L * 3072;
    const long base = ((long)b * 8192 + p) * 3072 + h * 64;

    {
        const int vrow = lane >> 3;
        const int vchunk = (lane & 7) ^ (vrow & 7);
#pragma unroll
        for (int q = 0; q < 8; ++q)
            gload16(qkv + base + (long)(q * 8 + vrow) * NSTR + 2048 + vchunk * 8,
                    (char*)Vlds + q * 1024);
    }

    s16x8 kf[4][2], qf[4][2];
#pragma unroll
    for (int t = 0; t < 4; ++t)
#pragma unroll
        for (int ks = 0; ks < 2; ++ks) {
            const long roff = base + (long)(t * 16 + rr) * NSTR + ks * 32 + g * 8;
            kf[t][ks] = *(const s16x8*)(qkv + roff + 1024);
            qf[t][ks] = *(const s16x8*)(qkv + roff);
        }

    f32x4 T[4][4] = {};
#pragma unroll
    for (int ks = 0; ks < 2; ++ks)
#pragma unroll
        for (int i = 0; i < 4; ++i)
#pragma unroll
            for (int jn = 0; jn < 4; ++jn)
                T[i][jn] = mfma16x16(kf[i][ks], qf[jn][ks], T[i][jn]);

    const float scale = 0.125f;
#pragma unroll
    for (int jn = 0; jn < 4; ++jn) {
        const int n = jn * 16 + rr;
        float pv[16];
        float mx = -3e38f;
#pragma unroll
        for (int i = 0; i < 4; ++i)
#pragma unroll
            for (int r = 0; r < 4; ++r) {
                const int m = i * 16 + g * 4 + r;
                const float s = (m <= n) ? T[i][jn][r] * scale : -3e38f;
                pv[i * 4 + r] = s;
                mx = fmaxf(mx, s);
            }
        mx = fmaxf(mx, __shfl_xor(mx, 16));
        mx = fmaxf(mx, __shfl_xor(mx, 32));
        float sum = 0.f;
#pragma unroll
        for (int t = 0; t < 16; ++t) {
            const float e = (pv[t] > -1e30f) ? __expf(pv[t] - mx) : 0.f;
            pv[t] = e;
            sum += e;
        }
        sum += __shfl_xor(sum, 16);
        sum += __shfl_xor(sum, 32);
        const float inv = 1.f / sum;
#pragma unroll
        for (int i = 0; i < 4; ++i)
#pragma unroll
            for (int rp = 0; rp < 2; ++rp) {
                const int m = i * 16 + g * 4 + rp * 2;
                const unsigned lo = f2bf(pv[i * 4 + rp * 2] * inv);
                const unsigned hi = f2bf(pv[i * 4 + rp * 2 + 1] * inv);
                *(unsigned*)((char*)Plds + n * 144 + m * 2) = lo | (hi << 16);
            }
    }

    wave_sync();

    f32x4 O[4][4] = {};
#pragma unroll
    for (int ks = 0; ks < 2; ++ks) {
        s16x8 pa[4];
#pragma unroll
        for (int in = 0; in < 4; ++in)
            pa[in] = *(const s16x8*)((const char*)Plds +
                      (in * 16 + rr) * 144 + ks * 64 + g * 16);
#pragma unroll
        for (int jd = 0; jd < 4; ++jd) {
            s16x8 vb;
#pragma unroll
            for (int j = 0; j < 8; ++j) {
                const int k = ks * 32 + g * 8 + j;
                const int byte = (k * 128 + (jd * 16 + rr) * 2) ^ ((k & 7) << 4);
                vb[j] = *(const short*)((const char*)Vlds + byte);
            }
#pragma unroll
            for (int in = 0; in < 4; ++in)
                O[in][jd] = mfma16x16(pa[in], vb, O[in][jd]);
        }
    }

    const long obase = ((long)b * 8192 + p) * 1024 + h * 64;
#pragma unroll
    for (int in = 0; in < 4; ++in)
#pragma unroll
        for (int r = 0; r < 4; ++r) {
            const long n = in * 16 + g * 4 + r;
#pragma unroll
            for (int jd = 0; jd < 4; ++jd) {
                const long d = jd * 16 + rr;
                o[obase + n * (128L * 1024) + d] = f2bf(O[in][jd][r]);
            }
        }
}

// ---------------------------------------------------------------------------
extern "C" void kernel_launch(void* const* d_in, const int* in_sizes, int n_in,
                              void* d_out, int out_size, void* d_ws, size_t ws_size,
                              hipStream_t stream) {
    const float* x    = (const float*)d_in[0];
    const float* Wqkv = (const float*)d_in[1];
    const float* bq   = (const float*)d_in[2];
    const float* Wout = (const float*)d_in[3];
    const float* bo   = (const float*)d_in[4];

    char* ws = (char*)d_ws;
    u16* xb    = (u16*)(ws);                 // 33,554,432 B
    u16* qkv   = (u16*)(ws +  33554432L);    // 100,663,296 B
    u16* ob    = (u16*)(ws + 134217728L);    // 33,554,432 B
    u16* WqkvT = (u16*)(ws + 167772160L);    // 6,291,456 B
    u16* WoutT = (u16*)(ws + 174063616L);    // 2,097,152 B
    const size_t NEEDED = 176160768UL;

    if (ws_size < NEEDED) {
        fill_sentinel<<<2048, 256, 0, stream>>>((float*)d_out, (long)out_size);
        return;
    }

    convert_x<<<2048, 256, 0, stream>>>(x, xb, 16777216L);
    transpose_f32_bf16<<<dim3(96, 32), 256, 0, stream>>>(Wqkv, WqkvT, 1024, 3072);
    transpose_f32_bf16<<<dim3(32, 32), 256, 0, stream>>>(Wout, WoutT, 1024, 1024);

    // qkv = x @ Wqkv + bqkv   (M=16384, N=3072, K=1024): 128 x 12 blocks
    gemm128x256<0, 16, 12><<<1536, 256, 0, stream>>>(xb, WqkvT, bq, qkv,
                                                     3072, 1024);

    attn_blocks<<<4096, 64, 0, stream>>>(qkv, ob);

    // out = o @ Wout + bout   (M=16384, N=1024, K=1024): 128 x 4 blocks
    gemm128x256<1, 16, 4><<<512, 256, 0, stream>>>(ob, WoutT, bo, d_out,
                                                   1024, 1024);
}